// Round 1
// baseline (947.186 us; speedup 1.0000x reference)
//
#include <hip/hip_runtime.h>
#include <hip/hip_bf16.h>

#define NEI     128
#define NUM_REL 5000
#define NSUP    32
#define D       128
#define K_TOP   64
#define NB      256
#define ROWSZ   (K_TOP * D)   // 8192

// d_out layout (FLOAT32 elements), outputs concatenated flat in return order
#define TN_OFF  0           // tree_node      [256][3][64]
#define TE_OFF  49152       // tree_emb_all   [256][3][64][128]
#define PI_OFF  6340608     // parent_index   [256][3][64]
#define PN_OFF  6389760     // parent_node    [256][3][64]
#define AR_OFF  6438912     // aim_rel_all    [256][3][64]

#define SENT 0xFFFFFFFFu

typedef __hip_bfloat16 bf16;
__device__ __forceinline__ float frbf(bf16 b) { return __bfloat162float(b); }
__device__ __forceinline__ unsigned umin2(unsigned a, unsigned b) { return a < b ? a : b; }

// Flag-dispatched float-input load: storage is either f32 or packed bf16.
__device__ __forceinline__ float ldin(const void* p, size_t idx, bool isbf) {
    return isbf ? frbf(((const bf16*)p)[idx]) : ((const float*)p)[idx];
}

// Detect storage dtype of a float-family array by inspecting low 16 bits of
// the first 64 words. bf16-packed: every half is a valid small-exponent bf16
// (exp in [100,135] for N(0,1)-scale data). f32: low mantissa bits ~uniform,
// P(exp in range) ~ 7% per word -> count >= 48 essentially impossible.
// Must be called by the whole block; result in *s_flag after barrier.
__device__ __forceinline__ void detect_bf16(const void* probe, int tid, int* s_flag) {
    if (tid < 64) {
        unsigned w = ((const unsigned*)probe)[tid];
        unsigned e = (w >> 7) & 0xFFu;
        unsigned long long m = __ballot(e >= 100 && e <= 135);
        if (tid == 0) *s_flag = (__popcll(m) >= 48) ? 1 : 0;
    }
    __syncthreads();
}

// ---------------------------------------------------------------------------
// rank[r] = #{r' : maxscore[r'] > maxscore[r]}, maxscore computed in-block.
// Equal scores share a rank -> key (rank<<13 | idx) reproduces jax.lax.top_k
// ordering (score desc, index asc) exactly (robust to exact-equal f32 too).
__global__ __launch_bounds__(256) void k_rank(const int* __restrict__ support,
                                              const void* __restrict__ cosm,
                                              int* __restrict__ rnk) {
    __shared__ float ms[NUM_REL];
    __shared__ int sup[NSUP];
    __shared__ int s_isbf;
    const int tid = threadIdx.x;
    detect_bf16(cosm, tid, &s_isbf);
    const bool isbf = (bool)s_isbf;
    if (tid < NSUP) sup[tid] = support[tid];
    __syncthreads();
    for (int i = tid; i < NUM_REL; i += 256) {
        float m = -INFINITY;
        #pragma unroll
        for (int s = 0; s < NSUP; s++)
            m = fmaxf(m, ldin(cosm, (size_t)sup[s] * NUM_REL + i, isbf));
        ms[i] = m;
    }
    __syncthreads();
    int r = blockIdx.x * 256 + tid;
    if (r < NUM_REL) {
        float mine = ms[r];
        int c = 0;
        for (int i = 0; i < NUM_REL; i++) c += (ms[i] > mine);
        rnk[r] = c;
    }
}

// ---------------------------------------------------------------------------
// Level 1: 128 candidates -> stable top-64 (bitonic sort of (rank,idx) keys),
// then gi = rel_emb[selr] @ W_ih^T + b_ih and h1 = GRU(x, h=0).
// h1 -> out tree_emb row 0 (f32); exact (ent,rel) stash as floats -> head of
// tree_emb row 1 (row 1 is fully overwritten by the level-2 kernel later).
__global__ __launch_bounds__(384) void k_level1(
    const int* __restrict__ query, const int* __restrict__ edge,
    const int* __restrict__ rnk, const void* __restrict__ cosm,
    const void* __restrict__ rel_emb,
    const void* __restrict__ W_ih, const void* __restrict__ b_ih,
    const void* __restrict__ b_hh, float* __restrict__ out)
{
    extern __shared__ char smem[];
    float* hs   = (float*)smem;              // [64][132]
    float* wts  = (float*)(smem + 33792);    // [384][8] during GEMM
    float* bufA = wts;                       // [8][385] during epilogue

    __shared__ unsigned keys[NEI];
    __shared__ int2 pairs[NEI];
    __shared__ int selr[K_TOP];
    __shared__ int s_isbf;

    const int tid = threadIdx.x;
    const int b = blockIdx.x;
    const int q = query[b];

    detect_bf16(cosm, tid, &s_isbf);
    const bool isbf = (bool)s_isbf;

    if (tid < NEI) {
        int2 pr = ((const int2*)edge)[(size_t)q * NEI + tid];
        pairs[tid] = pr;
        keys[tid] = ((unsigned)rnk[pr.y] << 13) | (unsigned)tid;
    }
    for (int size = 2; size <= NEI; size <<= 1) {
        for (int stride = size >> 1; stride > 0; stride >>= 1) {
            __syncthreads();
            if (tid < NEI) {
                int partner = tid ^ stride;
                if (partner > tid) {
                    unsigned a = keys[tid], c2 = keys[partner];
                    bool asc = ((tid & size) == 0);
                    if (asc ? (a > c2) : (a < c2)) { keys[tid] = c2; keys[partner] = a; }
                }
            }
        }
    }
    __syncthreads();
    if (tid < K_TOP) {
        int idx = keys[tid] & 8191;
        int2 p = pairs[idx];
        selr[tid] = p.y;
        float* su = out + TE_OFF + ((size_t)b * 3 + 1) * ROWSZ;
        su[tid]         = (float)p.x;   // exact e1 (ids < 5000, exact in f32)
        su[K_TOP + tid] = (float)p.y;   // exact r1
        out[TN_OFF + (b * 3 + 0) * K_TOP + tid] = (float)p.x;
        out[PN_OFF + (b * 3 + 0) * K_TOP + tid] = (float)q;
        out[PI_OFF + (b * 3 + 2) * K_TOP + tid] = (float)tid;  // arange row
    }
    __syncthreads();

    // X = rel_emb[selr]  (64x128)
    for (int idx = tid; idx < K_TOP * D; idx += 384) {
        int i = idx >> 7, d = idx & 127;
        hs[i * 132 + d] = ldin(rel_emb, (size_t)selr[i] * D + d, isbf);
    }

    const int gi_ = tid & 7;
    const int gj  = tid >> 3;  // 0..47
    float acc[8][8];
    #pragma unroll
    for (int m = 0; m < 8; m++)
        #pragma unroll
        for (int n = 0; n < 8; n++) acc[m][n] = 0.f;

    for (int kt = 0; kt < D; kt += 8) {
        __syncthreads();
        #pragma unroll
        for (int l = 0; l < 8; l++) {
            int idx = tid + l * 384;
            wts[idx] = ldin(W_ih, (size_t)(idx >> 3) * D + kt + (idx & 7), isbf);
        }
        __syncthreads();
        #pragma unroll
        for (int kc = 0; kc < 8; kc += 4) {
            float4 hv[8], wv[8];
            #pragma unroll
            for (int m = 0; m < 8; m++)
                hv[m] = *(const float4*)&hs[(gi_ + 8 * m) * 132 + kt + kc];
            #pragma unroll
            for (int n = 0; n < 8; n++)
                wv[n] = *(const float4*)&wts[(gj + 48 * n) * 8 + kc];
            #pragma unroll
            for (int m = 0; m < 8; m++)
                #pragma unroll
                for (int n = 0; n < 8; n++)
                    acc[m][n] += hv[m].x * wv[n].x + hv[m].y * wv[n].y
                               + hv[m].z * wv[n].z + hv[m].w * wv[n].w;
        }
    }

    float bih[8];
    #pragma unroll
    for (int n = 0; n < 8; n++) bih[n] = ldin(b_ih, gj + 48 * n, isbf);

    for (int c = 0; c < 8; c++) {
        __syncthreads();
        #pragma unroll
        for (int n = 0; n < 8; n++)
            bufA[gi_ * 385 + gj + 48 * n] = acc[c][n] + bih[n];
        __syncthreads();
        for (int idx = tid; idx < 8 * D; idx += 384) {
            int iloc = idx >> 7, d = idx & 127;
            int node = 8 * c + iloc;
            float i_r = bufA[iloc * 385 + d];
            float i_z = bufA[iloc * 385 + 128 + d];
            float i_n = bufA[iloc * 385 + 256 + d];
            float rg = 1.f / (1.f + expf(-(i_r + ldin(b_hh, d, isbf))));
            float z  = 1.f / (1.f + expf(-(i_z + ldin(b_hh, D + d, isbf))));
            float nn = tanhf(i_n + rg * ldin(b_hh, 2 * D + d, isbf));
            out[TE_OFF + ((size_t)b * 3 + 0) * ROWSZ + node * D + d] = (1.f - z) * nn;
        }
    }
}

// ---------------------------------------------------------------------------
// Levels 2/3: 8192 candidates -> top-64 (register keys, iterative block-min);
// gi = rel_emb[selr]@W_ih^T, gh = h_parent@W_hh^T, GRU gates, outputs.
// Reads exact parent ids from the f32 stash in tree_emb row (level-1),
// overwrites that row with the new hidden at the end; level 2 stashes its ids
// in row-2 head for level 3.
__global__ __launch_bounds__(384) void k_level(
    const int* __restrict__ edge, const int* __restrict__ rnk,
    const void* __restrict__ cosm, const void* __restrict__ rel_emb,
    const void* __restrict__ W_ih, const void* __restrict__ b_ih,
    const void* __restrict__ W_hh, const void* __restrict__ b_hh,
    float* __restrict__ out, const int level)
{
    extern __shared__ char smem[];
    float* hs   = (float*)smem;                      // [64][132]
    float* wts  = (float*)(smem + 33792);            // [384][8] during GEMMs
    float* bufA = (float*)(smem + 33792);            // [8][385] epilogue (gi)
    float* bufB = (float*)(smem + 33792 + 12320);    // [8][385] epilogue (gh)

    __shared__ int pe[K_TOP], prl[K_TOP], selp[K_TOP], selr[K_TOP];
    __shared__ unsigned topks[K_TOP];
    __shared__ unsigned wred[6];
    __shared__ int s_isbf;

    const int tid = threadIdx.x;
    const int b = blockIdx.x;
    const int2* edge2 = (const int2*)edge;

    detect_bf16(cosm, tid, &s_isbf);
    const bool isbf = (bool)s_isbf;

    if (tid < K_TOP) {
        const float* su = out + TE_OFF + ((size_t)b * 3 + (level - 1)) * ROWSZ;
        pe[tid]  = (int)su[tid];
        prl[tid] = (int)su[K_TOP + tid];
    }
    __syncthreads();

    // phase A: candidate keys in registers
    unsigned kreg[22];
    #pragma unroll
    for (int i = 0; i < 22; i++) {
        int j = tid + i * 384;
        unsigned k = SENT;
        if (j < K_TOP * NEI) {
            int rel = edge2[(size_t)pe[j >> 7] * NEI + (j & 127)].y;
            k = ((unsigned)rnk[rel] << 13) | (unsigned)j;
        }
        kreg[i] = k;
    }
    unsigned lmin = SENT;
    #pragma unroll
    for (int i = 0; i < 22; i++) lmin = umin2(lmin, kreg[i]);

    // phase B: 64 x block-min (keys unique -> unique winner each round)
    const int wid = tid >> 6;
    for (int it = 0; it < K_TOP; it++) {
        unsigned m = lmin;
        #pragma unroll
        for (int off = 32; off > 0; off >>= 1)
            m = umin2(m, (unsigned)__shfl_xor((int)m, off, 64));
        if ((tid & 63) == 0) wred[wid] = m;
        __syncthreads();
        unsigned g = umin2(umin2(umin2(wred[0], wred[1]), umin2(wred[2], wred[3])),
                           umin2(wred[4], wred[5]));
        if (tid == 0) topks[it] = g;
        if (lmin == g) {
            unsigned nl = SENT;
            #pragma unroll
            for (int i = 0; i < 22; i++) {
                if (kreg[i] == g) kreg[i] = SENT;
                nl = umin2(nl, kreg[i]);
            }
            lmin = nl;
        }
        __syncthreads();
    }

    // phase C: decode winners, scalar outputs, stash for next level
    if (tid < K_TOP) {
        int j = topks[tid] & 8191;
        int p = j >> 7, t = j & 127;
        int2 pr2 = edge2[(size_t)pe[p] * NEI + t];
        selp[tid] = p; selr[tid] = pr2.y;
        const int L1 = level - 1;
        out[TN_OFF + (b * 3 + L1) * K_TOP + tid]          = (float)pr2.x;
        out[PI_OFF + (b * 3 + (level - 2)) * K_TOP + tid] = (float)p;
        out[PN_OFF + (b * 3 + L1) * K_TOP + tid]          = (float)pe[p];
        out[AR_OFF + (b * 3 + (level - 2)) * K_TOP + tid] = (float)prl[p];
        if (level == 3)
            out[AR_OFF + (b * 3 + 2) * K_TOP + tid]       = (float)pr2.y;
        if (level == 2) {
            float* su = out + TE_OFF + ((size_t)b * 3 + 2) * ROWSZ;
            su[tid]         = (float)pr2.x;
            su[K_TOP + tid] = (float)pr2.y;
        }
    }
    __syncthreads();

    const int gi_ = tid & 7;
    const int gj  = tid >> 3;

    // GEMM 1: gi = rel_emb[selr] @ W_ih^T
    for (int idx = tid; idx < K_TOP * D; idx += 384) {
        int i = idx >> 7, d = idx & 127;
        hs[i * 132 + d] = ldin(rel_emb, (size_t)selr[i] * D + d, isbf);
    }
    float accA[8][8];
    #pragma unroll
    for (int m = 0; m < 8; m++)
        #pragma unroll
        for (int n = 0; n < 8; n++) accA[m][n] = 0.f;
    for (int kt = 0; kt < D; kt += 8) {
        __syncthreads();
        #pragma unroll
        for (int l = 0; l < 8; l++) {
            int idx = tid + l * 384;
            wts[idx] = ldin(W_ih, (size_t)(idx >> 3) * D + kt + (idx & 7), isbf);
        }
        __syncthreads();
        #pragma unroll
        for (int kc = 0; kc < 8; kc += 4) {
            float4 hv[8], wv[8];
            #pragma unroll
            for (int m = 0; m < 8; m++)
                hv[m] = *(const float4*)&hs[(gi_ + 8 * m) * 132 + kt + kc];
            #pragma unroll
            for (int n = 0; n < 8; n++)
                wv[n] = *(const float4*)&wts[(gj + 48 * n) * 8 + kc];
            #pragma unroll
            for (int m = 0; m < 8; m++)
                #pragma unroll
                for (int n = 0; n < 8; n++)
                    accA[m][n] += hv[m].x * wv[n].x + hv[m].y * wv[n].y
                                + hv[m].z * wv[n].z + hv[m].w * wv[n].w;
        }
    }

    // GEMM 2: gh = h_parent @ W_hh^T (h_parent gathered from prev tree_emb row)
    __syncthreads();
    for (int idx = tid; idx < K_TOP * D; idx += 384) {
        int i = idx >> 7, d = idx & 127;
        hs[i * 132 + d] =
            out[TE_OFF + ((size_t)b * 3 + (level - 2)) * ROWSZ + selp[i] * D + d];
    }
    float accB[8][8];
    #pragma unroll
    for (int m = 0; m < 8; m++)
        #pragma unroll
        for (int n = 0; n < 8; n++) accB[m][n] = 0.f;
    for (int kt = 0; kt < D; kt += 8) {
        __syncthreads();
        #pragma unroll
        for (int l = 0; l < 8; l++) {
            int idx = tid + l * 384;
            wts[idx] = ldin(W_hh, (size_t)(idx >> 3) * D + kt + (idx & 7), isbf);
        }
        __syncthreads();
        #pragma unroll
        for (int kc = 0; kc < 8; kc += 4) {
            float4 hv[8], wv[8];
            #pragma unroll
            for (int m = 0; m < 8; m++)
                hv[m] = *(const float4*)&hs[(gi_ + 8 * m) * 132 + kt + kc];
            #pragma unroll
            for (int n = 0; n < 8; n++)
                wv[n] = *(const float4*)&wts[(gj + 48 * n) * 8 + kc];
            #pragma unroll
            for (int m = 0; m < 8; m++)
                #pragma unroll
                for (int n = 0; n < 8; n++)
                    accB[m][n] += hv[m].x * wv[n].x + hv[m].y * wv[n].y
                                + hv[m].z * wv[n].z + hv[m].w * wv[n].w;
        }
    }

    float bih[8];
    #pragma unroll
    for (int n = 0; n < 8; n++) bih[n] = ldin(b_ih, gj + 48 * n, isbf);

    // epilogue: gates in 8-node chunks via LDS
    for (int c = 0; c < 8; c++) {
        __syncthreads();
        #pragma unroll
        for (int n = 0; n < 8; n++) {
            bufA[gi_ * 385 + gj + 48 * n] = accA[c][n] + bih[n];
            bufB[gi_ * 385 + gj + 48 * n] = accB[c][n];
        }
        __syncthreads();
        for (int idx = tid; idx < 8 * D; idx += 384) {
            int iloc = idx >> 7, d = idx & 127;
            int node = 8 * c + iloc;
            float i_r = bufA[iloc * 385 + d];
            float i_z = bufA[iloc * 385 + 128 + d];
            float i_n = bufA[iloc * 385 + 256 + d];
            float h_r = bufB[iloc * 385 + d] + ldin(b_hh, d, isbf);
            float h_z = bufB[iloc * 385 + 128 + d] + ldin(b_hh, D + d, isbf);
            float h_n = bufB[iloc * 385 + 256 + d] + ldin(b_hh, 2 * D + d, isbf);
            float rg = 1.f / (1.f + expf(-(i_r + h_r)));
            float z  = 1.f / (1.f + expf(-(i_z + h_z)));
            float nn = tanhf(i_n + rg * h_n);
            float hprev = hs[node * 132 + d];
            float hnew = (1.f - z) * nn + z * hprev;
            out[TE_OFF + ((size_t)b * 3 + (level - 1)) * ROWSZ + node * D + d] = hnew;
        }
    }
}

// ---------------------------------------------------------------------------
extern "C" void kernel_launch(void* const* d_in, const int* in_sizes, int n_in,
                              void* d_out, int out_size, void* d_ws, size_t ws_size,
                              hipStream_t stream)
{
    const int*  query   = (const int*)d_in[0];
    const int*  edge    = (const int*)d_in[1];
    const int*  support = (const int*)d_in[2];
    const void* cosm    = d_in[3];   // f32 or bf16 -- detected on device
    const void* rel_emb = d_in[4];
    const void* W_ih    = d_in[5];
    const void* W_hh    = d_in[6];
    const void* b_ih    = d_in[7];
    const void* b_hh    = d_in[8];
    float* out = (float*)d_out;      // f32 (confirmed: round-4 integer absmax)

    int* rnk = (int*)d_ws;  // 5000 int32 = 20 KB, only ws use

    k_rank<<<(NUM_REL + 255) / 256, 256, 0, stream>>>(support, cosm, rnk);
    k_level1<<<NB, 384, 46112, stream>>>(query, edge, rnk, cosm,
                                         rel_emb, W_ih, b_ih, b_hh, out);
    k_level<<<NB, 384, 58432, stream>>>(edge, rnk, cosm, rel_emb,
                                        W_ih, b_ih, W_hh, b_hh, out, 2);
    k_level<<<NB, 384, 58432, stream>>>(edge, rnk, cosm, rel_emb,
                                        W_ih, b_ih, W_hh, b_hh, out, 3);
}